// Round 1
// baseline (731.340 us; speedup 1.0000x reference)
//
#include <hip/hip_runtime.h>

// Problem constants
#define B_   512
#define L_   500
#define D_   300
#define A_   5
#define H_   10

// ---------- bf16 helpers (manual, no API-version risk) ----------
__device__ __forceinline__ unsigned f2bf(float f) {
    union { float f; unsigned u; } c; c.f = f;
    unsigned r = c.u;
    r += 0x7fffu + ((r >> 16) & 1u);   // round-to-nearest-even
    return r >> 16;
}
__device__ __forceinline__ float bf2f(unsigned u16) {
    union { unsigned u; float f; } c; c.u = u16 << 16;
    return c.f;
}

// ---------------------------------------------------------------
// K1: proj[b,a,l,h] = sum_d X[b,l,d] * W[a,d,h], stored as bf16 in ws.
// grid (2, 512): blockIdx.x = 256-row tile, blockIdx.y = b.
// block 320 threads = 5 waves; wave av = aspect. Lane owns rows
// {lane, lane+64, lane+128, lane+192} x 10 h accumulators.
// K staged in chunks of 30.
// ---------------------------------------------------------------
__global__ __launch_bounds__(320) void k_proj(const float* __restrict__ X,
                                              const float* __restrict__ W,
                                              unsigned short* __restrict__ P)
{
    __shared__ float lx[256][30];   // X tile   (30720 B) row stride 30: 2-way bank alias = free
    __shared__ float lwt[30][50];   // W chunk  (6000 B), broadcast reads

    const int b    = blockIdx.y;
    const int l0   = blockIdx.x << 8;
    const int tid  = threadIdx.x;
    const int av   = tid >> 6;      // aspect (0..4)
    const int lane = tid & 63;
    const int kk_s = tid & 31;      // staging col
    const int rg   = tid >> 5;      // staging row group (0..9)

    float acc[4][10];
#pragma unroll
    for (int i = 0; i < 4; ++i)
#pragma unroll
        for (int j = 0; j < 10; ++j) acc[i][j] = 0.f;

    for (int c = 0; c < 10; ++c) {
        const int k0 = c * 30;

        // ---- stage X tile (rows l0..l0+255, cols k0..k0+29) ----
        if (kk_s < 30) {
            for (int r = rg; r < 256; r += 10) {
                const int gl = l0 + r;
                float v = 0.f;
                if (gl < L_) v = X[(b * L_ + gl) * D_ + k0 + kk_s];
                lx[r][kk_s] = v;
            }
        }
        // ---- stage W chunk [30][50] ----
        for (int i = tid; i < 1500; i += 320) {
            const int kk = i / 50;
            const int hh = i - kk * 50;
            const int a2 = hh / 10;
            const int h2 = hh - a2 * 10;
            lwt[kk][hh] = W[(a2 * D_ + k0 + kk) * H_ + h2];
        }
        __syncthreads();

        // ---- inner product: 80 FMA per 2-k step per thread ----
#pragma unroll 3
        for (int kk = 0; kk < 30; kk += 2) {
            float2 wlo[5], whi[5];
#pragma unroll
            for (int j = 0; j < 5; ++j) {
                wlo[j] = *(const float2*)&lwt[kk    ][av * 10 + 2 * j];
                whi[j] = *(const float2*)&lwt[kk + 1][av * 10 + 2 * j];
            }
#pragma unroll
            for (int ri = 0; ri < 4; ++ri) {
                const float2 x2 = *(const float2*)&lx[(ri << 6) + lane][kk];
#pragma unroll
                for (int j = 0; j < 5; ++j) {
                    acc[ri][2*j]   = fmaf(x2.x, wlo[j].x, acc[ri][2*j]);
                    acc[ri][2*j]   = fmaf(x2.y, whi[j].x, acc[ri][2*j]);
                    acc[ri][2*j+1] = fmaf(x2.x, wlo[j].y, acc[ri][2*j+1]);
                    acc[ri][2*j+1] = fmaf(x2.y, whi[j].y, acc[ri][2*j+1]);
                }
            }
        }
        __syncthreads();
    }

    // ---- store proj as bf16 (packed pairs -> dword stores) ----
#pragma unroll
    for (int ri = 0; ri < 4; ++ri) {
        const int gl = l0 + (ri << 6) + lane;
        if (gl < L_) {
            unsigned* dst = (unsigned*)(P + ((size_t)((b * A_ + av) * L_ + gl)) * H_);
#pragma unroll
            for (int j = 0; j < 5; ++j) {
                const unsigned lo = f2bf(acc[ri][2*j]);
                const unsigned hi = f2bf(acc[ri][2*j+1]);
                dst[j] = lo | (hi << 16);
            }
        }
    }
}

// ---------------------------------------------------------------
// K2: per (b,a): score (ctx-3 window) -> softmax over L -> attn out,
// then rep[h] = sum_l attn[l]*proj[l,h].
// grid (5, 512): blockIdx.x = a, blockIdx.y = b. block 256 = 4 waves.
// ---------------------------------------------------------------
__global__ __launch_bounds__(256) void k_attn(const unsigned short* __restrict__ P,
                                              const float* __restrict__ E,
                                              float* __restrict__ out)
{
    __shared__ float lp[L_][H_];    // proj tile f32 (20000 B)
    __shared__ float red_m[4];
    __shared__ float red_z[4];
    __shared__ float red10[4][10];

    const int a    = blockIdx.x;
    const int b    = blockIdx.y;
    const int t    = threadIdx.x;
    const int wid  = t >> 6;
    const int lane = t & 63;

    // ---- stage proj (5000 bf16 = 625 uint4) and widen to f32 ----
    const uint4* src = (const uint4*)(P + ((size_t)(b * A_ + a)) * L_ * H_);
    float* lpf = (float*)lp;
    for (int i = t; i < 625; i += 256) {
        const uint4 v = src[i];
        const int o = i * 8;
        lpf[o + 0] = bf2f(v.x & 0xffffu); lpf[o + 1] = bf2f(v.x >> 16);
        lpf[o + 2] = bf2f(v.y & 0xffffu); lpf[o + 3] = bf2f(v.y >> 16);
        lpf[o + 4] = bf2f(v.z & 0xffffu); lpf[o + 5] = bf2f(v.z >> 16);
        lpf[o + 6] = bf2f(v.w & 0xffffu); lpf[o + 7] = bf2f(v.w >> 16);
    }

    // E[a] -> registers (wave-uniform broadcast loads)
    float e[3][10];
#pragma unroll
    for (int w = 0; w < 3; ++w)
#pragma unroll
        for (int h = 0; h < 10; ++h)
            e[w][h] = E[a * 30 + w * 10 + h];

    __syncthreads();

    // ---- score for l = t and l = t + 256 (zero-padded window) ----
    const int l1 = t + 256;
    float s0 = 0.f, s1 = 0.f;
#pragma unroll
    for (int w = 0; w < 3; ++w) {
        const int lw0 = t + w - 1;
        if (lw0 >= 0 && lw0 < L_) {
#pragma unroll
            for (int h = 0; h < 10; ++h) s0 = fmaf(lp[lw0][h], e[w][h], s0);
        }
        const int lw1 = l1 + w - 1;
        if (l1 < L_ && lw1 < L_) {   // lw1 >= 0 always here
#pragma unroll
            for (int h = 0; h < 10; ++h) s1 = fmaf(lp[lw1][h], e[w][h], s1);
        }
    }
    const bool has1 = (l1 < L_);

    // ---- block max ----
    float m = has1 ? fmaxf(s0, s1) : s0;
#pragma unroll
    for (int off = 32; off >= 1; off >>= 1) m = fmaxf(m, __shfl_xor(m, off));
    if (lane == 0) red_m[wid] = m;
    __syncthreads();
    m = fmaxf(fmaxf(red_m[0], red_m[1]), fmaxf(red_m[2], red_m[3]));

    // ---- block sum of exp ----
    const float e0 = expf(s0 - m);
    const float e1 = has1 ? expf(s1 - m) : 0.f;
    float z = e0 + e1;
#pragma unroll
    for (int off = 32; off >= 1; off >>= 1) z += __shfl_xor(z, off);
    if (lane == 0) red_z[wid] = z;
    __syncthreads();
    const float Z   = red_z[0] + red_z[1] + red_z[2] + red_z[3];
    const float inv = 1.f / Z;

    // ---- attn out ----
    float* attn_out = out + (size_t)(b * A_ + a) * L_;
    const float a0 = e0 * inv;
    attn_out[t] = a0;
    float a1 = 0.f;
    if (has1) { a1 = e1 * inv; attn_out[l1] = a1; }

    // ---- rep: per-thread partials over own l's, then reduce ----
    float ph[10];
#pragma unroll
    for (int h = 0; h < 10; ++h) {
        float v = a0 * lp[t][h];
        if (has1) v = fmaf(a1, lp[l1][h], v);
        ph[h] = v;
    }
#pragma unroll
    for (int h = 0; h < 10; ++h) {
#pragma unroll
        for (int off = 32; off >= 1; off >>= 1) ph[h] += __shfl_xor(ph[h], off);
    }
    if (lane == 0) {
#pragma unroll
        for (int h = 0; h < 10; ++h) red10[wid][h] = ph[h];
    }
    __syncthreads();
    if (t < 10) {
        const float r = red10[0][t] + red10[1][t] + red10[2][t] + red10[3][t];
        out[(size_t)B_ * A_ * L_ + (size_t)(b * A_ + a) * H_ + t] = r;
    }
}

extern "C" void kernel_launch(void* const* d_in, const int* in_sizes, int n_in,
                              void* d_out, int out_size, void* d_ws, size_t ws_size,
                              hipStream_t stream)
{
    const float* X = (const float*)d_in[0];   // review_emb (512,500,300)
    const float* E = (const float*)d_in[1];   // asp_embed  (5,30)
    const float* W = (const float*)d_in[2];   // asp_proj   (5,300,10)
    float* out = (float*)d_out;
    unsigned short* P = (unsigned short*)d_ws;  // proj bf16: 512*5*500*10*2 = 25.6 MB

    dim3 g1(2, B_), b1(320);
    k_proj<<<g1, b1, 0, stream>>>(X, W, P);

    dim3 g2(A_, B_), b2(256);
    k_attn<<<g2, b2, 0, stream>>>(P, E, out);
}

// Round 2
// 699.464 us; speedup vs baseline: 1.0456x; 1.0456x over previous
//
#include <hip/hip_runtime.h>

#define B_   512
#define L_   500
#define D_   300
#define A_   5
#define H_   10
#define NJ   50     // A_*H_ output columns per row
#define WROW 52     // padded W row in floats (208 B, 16B-aligned rows for ds_read_b128)
#define PROW 27     // padded proj row in uints (25 used; 27 coprime 32 -> 2-way = free)

// ---------- bf16 helpers ----------
__device__ __forceinline__ unsigned f2bf(float f) {
    union { float f; unsigned u; } c; c.f = f;
    unsigned r = c.u;
    r += 0x7fffu + ((r >> 16) & 1u);   // RNE
    return r >> 16;
}
__device__ __forceinline__ float bf2f(unsigned u16) {
    union { unsigned u; float f; } c; c.u = u16 << 16;
    return c.f;
}

__device__ __forceinline__ float wred_max(float v) {
#pragma unroll
    for (int off = 32; off >= 1; off >>= 1) v = fmaxf(v, __shfl_xor(v, off));
    return v;
}
__device__ __forceinline__ float wred_sum(float v) {
#pragma unroll
    for (int off = 32; off >= 1; off >>= 1) v += __shfl_xor(v, off);
    return v;
}

// One block per b. Thread t owns review position l=t (t<500).
// Phase 1: proj row via global->reg streaming of X row, W broadcast from LDS.
// Phase 2: windowed score + block softmax. Phase 3: attention-weighted pooling.
__global__ __launch_bounds__(512) void k_fused(const float* __restrict__ X,
                                               const float* __restrict__ E,
                                               const float* __restrict__ W,
                                               float* __restrict__ out)
{
    __shared__ __align__(16) float ws_w[D_ * WROW];   // 62,400 B  W[k][a*10+h]
    __shared__ unsigned ws_p[L_ * PROW];              // 54,000 B  proj bf16 pairs
    __shared__ float ws_e[160];                       // 640 B     E[a][w][h]
    __shared__ float redbuf[8][NJ];                   // 1,600 B   cross-wave reductions

    const int b    = blockIdx.x;
    const int t    = threadIdx.x;
    const int wid  = t >> 6;
    const int lane = t & 63;
    const bool valid = (t < L_);

    // ---- early prefetch of first X chunk (hides HBM latency under W staging) ----
    const float4* xrow = (const float4*)(X + (size_t)(b * L_ + (valid ? t : 0)) * D_);
    float4 xb0 = xrow[0], xb1 = xrow[1], xb2 = xrow[2];

    // ---- stage W (60 KB, read once; L2/L3-resident across blocks) + E ----
    for (int i = t; i < D_ * NJ; i += 512) {
        const int k = i / NJ, r = i - k * NJ;
        const int a = r / H_, h = r - a * H_;
        ws_w[k * WROW + r] = W[(a * D_ + k) * H_ + h];
    }
    if (t < A_ * 30) ws_e[t] = E[t];
    __syncthreads();

    // ================= Phase 1: proj = X_row @ W  (acc[50] in regs) =================
    if (valid) {
        float acc[NJ];
#pragma unroll
        for (int j = 0; j < NJ; ++j) acc[j] = 0.f;

#pragma unroll 1
        for (int it = 0; it < 25; ++it) {
            // prefetch next 3 float4 (clamped re-read on last iter: always in-bounds)
            const int nb = (it < 24) ? (it + 1) * 3 : 72;
            const float4 xn0 = xrow[nb], xn1 = xrow[nb + 1], xn2 = xrow[nb + 2];
            const int k0 = it * 12;
#pragma unroll
            for (int q = 0; q < 3; ++q) {
                const float4 xq = (q == 0) ? xb0 : ((q == 1) ? xb1 : xb2);
#pragma unroll
                for (int c = 0; c < 4; ++c) {
                    const float xs = (c == 0) ? xq.x : ((c == 1) ? xq.y : ((c == 2) ? xq.z : xq.w));
                    const float* wr = &ws_w[(k0 + q * 4 + c) * WROW];
#pragma unroll
                    for (int j4 = 0; j4 < 12; ++j4) {       // broadcast ds_read_b128
                        const float4 wv = *(const float4*)&wr[j4 * 4];
                        acc[j4*4+0] = fmaf(xs, wv.x, acc[j4*4+0]);
                        acc[j4*4+1] = fmaf(xs, wv.y, acc[j4*4+1]);
                        acc[j4*4+2] = fmaf(xs, wv.z, acc[j4*4+2]);
                        acc[j4*4+3] = fmaf(xs, wv.w, acc[j4*4+3]);
                    }
                    const float2 wt = *(const float2*)&wr[48];
                    acc[48] = fmaf(xs, wt.x, acc[48]);
                    acc[49] = fmaf(xs, wt.y, acc[49]);
                }
            }
            xb0 = xn0; xb1 = xn1; xb2 = xn2;
        }

        // pack proj row to bf16 pairs in LDS (lane stride 27 -> 2-way, free)
#pragma unroll
        for (int u = 0; u < 25; ++u) {
            const unsigned lo = f2bf(acc[2*u]), hi = f2bf(acc[2*u+1]);
            ws_p[t * PROW + u] = lo | (hi << 16);
        }
    }
    __syncthreads();

    // ================= Phase 2: windowed score + softmax over l =================
    float sc[A_];
    if (valid) {
#pragma unroll
        for (int a = 0; a < A_; ++a) {
            float s = 0.f;
#pragma unroll
            for (int w = 0; w < 3; ++w) {
                const int lw = t + w - 1;
                if (lw >= 0 && lw < L_) {
#pragma unroll
                    for (int u = 0; u < 5; ++u) {
                        const unsigned pv = ws_p[lw * PROW + a * 5 + u];
                        s = fmaf(bf2f(pv & 0xffffu), ws_e[a*30 + w*10 + 2*u],     s);
                        s = fmaf(bf2f(pv >> 16),     ws_e[a*30 + w*10 + 2*u + 1], s);
                    }
                }
            }
            sc[a] = s;
        }
    } else {
#pragma unroll
        for (int a = 0; a < A_; ++a) sc[a] = -1e30f;
    }

    // block max per aspect
#pragma unroll
    for (int a = 0; a < A_; ++a) {
        const float m = wred_max(sc[a]);
        if (lane == 0) redbuf[wid][a] = m;
    }
    __syncthreads();
    float mB[A_];
#pragma unroll
    for (int a = 0; a < A_; ++a) {
        float m = redbuf[0][a];
#pragma unroll
        for (int w2 = 1; w2 < 8; ++w2) m = fmaxf(m, redbuf[w2][a]);
        mB[a] = m;
    }
    __syncthreads();   // reads done before redbuf reuse

    // block sum of exp per aspect
    float eB[A_];
#pragma unroll
    for (int a = 0; a < A_; ++a) {
        eB[a] = valid ? __expf(sc[a] - mB[a]) : 0.f;
        const float z = wred_sum(eB[a]);
        if (lane == 0) redbuf[wid][a] = z;
    }
    __syncthreads();

    float att[A_];
    float* aout = out + (size_t)b * (A_ * L_);
#pragma unroll
    for (int a = 0; a < A_; ++a) {
        float Z = 0.f;
#pragma unroll
        for (int w2 = 0; w2 < 8; ++w2) Z += redbuf[w2][a];
        att[a] = eB[a] * (1.0f / Z);
        if (valid) aout[a * L_ + t] = att[a];
    }
    __syncthreads();   // before redbuf reuse in phase 3

    // ================= Phase 3: rep[a][h] = sum_l attn * proj =================
    float p50[NJ];
    if (valid) {
#pragma unroll
        for (int a = 0; a < A_; ++a) {
            const float aa = att[a];
#pragma unroll
            for (int u = 0; u < 5; ++u) {
                const unsigned pv = ws_p[t * PROW + a * 5 + u];
                p50[a*10 + 2*u]     = aa * bf2f(pv & 0xffffu);
                p50[a*10 + 2*u + 1] = aa * bf2f(pv >> 16);
            }
        }
    } else {
#pragma unroll
        for (int j = 0; j < NJ; ++j) p50[j] = 0.f;
    }
#pragma unroll
    for (int j = 0; j < NJ; ++j) {
        const float r = wred_sum(p50[j]);
        if (lane == 0) redbuf[wid][j] = r;
    }
    __syncthreads();
    if (t < NJ) {
        float r = 0.f;
#pragma unroll
        for (int w2 = 0; w2 < 8; ++w2) r += redbuf[w2][t];
        out[(size_t)B_ * A_ * L_ + (size_t)b * NJ + t] = r;
    }
}

extern "C" void kernel_launch(void* const* d_in, const int* in_sizes, int n_in,
                              void* d_out, int out_size, void* d_ws, size_t ws_size,
                              hipStream_t stream)
{
    const float* X = (const float*)d_in[0];   // review_emb (512,500,300)
    const float* E = (const float*)d_in[1];   // asp_embed  (5,30)
    const float* W = (const float*)d_in[2];   // asp_proj   (5,300,10)
    float* out = (float*)d_out;

    k_fused<<<B_, 512, 0, stream>>>(X, E, W, out);
}